// Round 1
// 499.052 us; speedup vs baseline: 1.0295x; 1.0295x over previous
//
#include <hip/hip_runtime.h>
#include <stdint.h>

typedef unsigned short u16t;
typedef __attribute__((ext_vector_type(8))) short frag8;   // 8 x bf16 (4 VGPRs)
typedef __attribute__((ext_vector_type(4))) float facc4;   // MFMA accumulator

#define S_LEN 2048
#define E_DIM 2048
#define LDSH  8192          // u16 per half-tile (128 lines x 64 u16)

__device__ __forceinline__ u16t f2bf(float f) {
    union { float f; uint32_t u; } c; c.f = f;
    return (u16t)((c.u + 0x7fffu + ((c.u >> 16) & 1u)) >> 16);  // RNE
}

// ---------------- fp32 -> bf16 conversion (vectorized) ----------------
__global__ __launch_bounds__(256) void cvt_kernel(const float* __restrict__ src,
                                                  u16t* __restrict__ dst, int n4) {
    int i = blockIdx.x * 256 + threadIdx.x;
    if (i >= n4) return;
    float4 v = ((const float4*)src)[i];
    ushort4 o;
    o.x = f2bf(v.x); o.y = f2bf(v.y); o.z = f2bf(v.z); o.w = f2bf(v.w);
    ((ushort4*)dst)[i] = o;
}

// ---------------- async global->LDS, 16B per lane ----------------
__device__ __forceinline__ void gldl16(const u16t* g, u16t* l) {
    __builtin_amdgcn_global_load_lds(
        (__attribute__((address_space(1))) void*)(g),
        (__attribute__((address_space(3))) void*)(l), 16, 0, 0);
}

// =====================================================================
// 256x256 8-phase GEMM core:  C[256x256] = A[256xK] * B[256xK]^T
// 8 waves (2M x 4N), per-wave C = 128x64 -> acc[8][4].
// K-tile BK=64 split into 2 ksub halves (k 0..31 / 32..63); each half =
// 128 lines x 64 u16 (16 KB) holding ALL 256 rows: row r lives at
// line = r&127, chunk-col = ((r>>7)*4 + q) ^ (r&7)  (q = 16B chunk in ksub).
// XOR swizzle applied via pre-swizzled GLOBAL source (global_load_lds dest
// stays lane-linear, rule 21); frag ds_read_b128 uses the same XOR -> the
// proven conflict-free 8-lanes-per-column pattern (G4 recipe).
// Schedule per K-tile (4 phases, counted vmcnt at phases 1 & 3 only):
//   p1: issue A-k0(t+1); vmcnt(6); s_barrier; read bv(k0)+av0-3(k0); 16 MFMA
//   p2: issue B-k0(t+1);                     read av4-7(k0);        16 MFMA
//   p3: issue A-k1(t+1); vmcnt(6); s_barrier; read bv(k1)+av0-3(k1); 16 MFMA
//   p4: issue B-k1(t+1);                     read av4-7(k1);        16 MFMA
// Steady state: 10 outstanding at each wait, oldest 4 = halves read next,
// 6 (3 half-tiles) stay in flight across the barriers (never drained).
// =====================================================================
__device__ __forceinline__ void gemm256(const u16t* __restrict__ A,
                                        const u16t* __restrict__ B,
                                        int bm0, int bn0,
                                        u16t* lds, facc4 acc[8][4]) {
    const int t     = threadIdx.x;
    const int lane  = t & 63;
    const int wid   = t >> 6;
    const int m16   = lane & 15;
    const int quad  = lane >> 4;
    const int wid_m = wid >> 2;     // 0..1
    const int wid_n = wid & 3;      // 0..3

#pragma unroll
    for (int i = 0; i < 8; ++i)
#pragma unroll
        for (int j = 0; j < 4; ++j) acc[i][j] = facc4{0.f, 0.f, 0.f, 0.f};

    // ---- frag read offsets (u16 units), swizzled ----
    const int colA = (((wid_m << 2) + quad) ^ (m16 & 7)) << 3;
    const int colB = ((((wid_n >> 1) << 2) + quad) ^ (m16 & 7)) << 3;
    const int roA  = m16 * 64 + colA;                        // + i*1024
    const int roB  = ((wid_n & 1) * 64 + m16) * 64 + colB;   // + j*1024

    // ---- staging lane geometry (inverse swizzle on global source) ----
    const int cp    = (lane & 7) ^ (lane >> 3);
    const int rgrp  = cp >> 2;
    const int qq    = cp & 3;
    const int line0 = wid * 8 + (lane >> 3);
    const u16t* pA[2]; const u16t* pB[2]; int dOf[2];
#pragma unroll
    for (int ld = 0; ld < 2; ++ld) {
        const int grow = rgrp * 128 + ld * 64 + line0;   // row within 256-tile
        pA[ld] = A + (size_t)(bm0 + grow) * E_DIM + qq * 8;
        pB[ld] = B + (size_t)(bn0 + grow) * E_DIM + qq * 8;
        dOf[ld] = (ld * 512 + wid * 64) * 8;             // lane-linear dest
    }

    // ---- prologue: stage tile 0 into dbuf 0 (order: A0 B0 A1 B1) ----
#pragma unroll
    for (int ld = 0; ld < 2; ++ld) gldl16(pA[ld],      lds +         dOf[ld]);
#pragma unroll
    for (int ld = 0; ld < 2; ++ld) gldl16(pB[ld],      lds + 16384 + dOf[ld]);
#pragma unroll
    for (int ld = 0; ld < 2; ++ld) gldl16(pA[ld] + 32, lds + LDSH  + dOf[ld]);
#pragma unroll
    for (int ld = 0; ld < 2; ++ld) gldl16(pB[ld] + 32, lds + 24576 + dOf[ld]);

#define MFMA16(IB)                                                            \
    __builtin_amdgcn_s_setprio(1);                                            \
    _Pragma("unroll")                                                         \
    for (int i = 0; i < 4; ++i)                                               \
        _Pragma("unroll")                                                     \
        for (int j = 0; j < 4; ++j)                                           \
            acc[i + IB][j] = __builtin_amdgcn_mfma_f32_16x16x32_bf16(         \
                av[i], bv[j], acc[i + IB][j], 0, 0, 0);                       \
    __builtin_amdgcn_s_setprio(0);

#pragma unroll 2
    for (int t0 = 0; t0 < 32; ++t0) {
        const u16t* Lc = lds + (t0 & 1) * 32768;          // compute buffer
        u16t* Ln       = lds + ((t0 & 1) ^ 1) * 32768;    // stage buffer
        const int kn   = (t0 < 31) ? (t0 + 1) * 64 : 0;   // wrap on last tile
        frag8 av[4], bv[4];

        // ===== phase 1: ksub0, i = 0..3 =====
        gldl16(pA[0] + kn, Ln + dOf[0]);
        gldl16(pA[1] + kn, Ln + dOf[1]);
        asm volatile("s_waitcnt vmcnt(6)" ::: "memory");
        __builtin_amdgcn_s_barrier();
#pragma unroll
        for (int j = 0; j < 4; ++j) bv[j] = *(const frag8*)(Lc + 16384 + roB + j * 1024);
#pragma unroll
        for (int i = 0; i < 4; ++i) av[i] = *(const frag8*)(Lc + roA + i * 1024);
        MFMA16(0)

        // ===== phase 2: ksub0, i = 4..7 =====
        gldl16(pB[0] + kn, Ln + 16384 + dOf[0]);
        gldl16(pB[1] + kn, Ln + 16384 + dOf[1]);
#pragma unroll
        for (int i = 0; i < 4; ++i) av[i] = *(const frag8*)(Lc + roA + (i + 4) * 1024);
        MFMA16(4)

        // ===== phase 3: ksub1, i = 0..3 =====
        gldl16(pA[0] + kn + 32, Ln + LDSH + dOf[0]);
        gldl16(pA[1] + kn + 32, Ln + LDSH + dOf[1]);
        asm volatile("s_waitcnt vmcnt(6)" ::: "memory");
        __builtin_amdgcn_s_barrier();
#pragma unroll
        for (int j = 0; j < 4; ++j) bv[j] = *(const frag8*)(Lc + 24576 + roB + j * 1024);
#pragma unroll
        for (int i = 0; i < 4; ++i) av[i] = *(const frag8*)(Lc + LDSH + roA + i * 1024);
        MFMA16(0)

        // ===== phase 4: ksub1, i = 4..7 =====
        gldl16(pB[0] + kn + 32, Ln + 24576 + dOf[0]);
        gldl16(pB[1] + kn + 32, Ln + 24576 + dOf[1]);
#pragma unroll
        for (int i = 0; i < 4; ++i) av[i] = *(const frag8*)(Lc + LDSH + roA + (i + 4) * 1024);
        MFMA16(4)
    }
#undef MFMA16

    // drain the tail prefetch before epilogue / endpgm
    asm volatile("s_waitcnt vmcnt(0)" ::: "memory");
}

// bijective XCD-aware tile swizzle: 256 wgs per plane, 256 % 8 == 0.
__device__ __forceinline__ void tile_swz(int& bm0, int& bn0) {
    const int orig = blockIdx.y * 8 + blockIdx.x;
    const int swz  = (orig & 7) * 32 + (orig >> 3);
    bm0 = (swz >> 3) * 256;
    bn0 = (swz & 7) * 256;
}

// ---------------- fused QKV projection (+bias, +RoPE for q,k) ----------------
struct QkvArgs {
    const u16t* w[3];
    const float* bias[3];
    u16t* out[3];
};

__global__ __launch_bounds__(512, 2)
void qkv_gemm(const u16t* __restrict__ xb, QkvArgs args,
              const float* __restrict__ fcos, const float* __restrict__ fsin) {
    __shared__ u16t lds[65536];     // 128 KiB: 2 dbuf x (A k0,k1 + B k0,k1)
    facc4 acc[8][4];
    int bm0, bn0; tile_swz(bm0, bn0);
    const int z = blockIdx.z;
    gemm256(xb, args.w[z], bm0, bn0, lds, acc);

    const int t     = threadIdx.x;
    const int lane  = t & 63;
    const int m16   = lane & 15;
    const int quad  = lane >> 4;
    const int wid   = t >> 6;
    const int wid_m = wid >> 2;
    const int wid_n = wid & 3;
    const bool rope = (z < 2);
    u16t* out = args.out[z];
    const float* bias = args.bias[z];

#pragma unroll
    for (int i = 0; i < 8; ++i) {
#pragma unroll
        for (int j = 0; j < 4; ++j) {
            const int n = bn0 + wid_n * 64 + j * 16 + m16;
            const float bn_ = bias[n];
#pragma unroll
            for (int r = 0; r < 4; ++r) {
                const int m = bm0 + wid_m * 128 + i * 16 + quad * 4 + r;
                float v = acc[i][j][r] + bn_;
                // RoPE: pair partner (n^1) lives in lane^1 (same quad, same reg)
                const float part = __shfl_xor(v, 1, 64);
                if (rope) {
                    const int s = m & (S_LEN - 1);
                    const int p = (n & 127) >> 1;
                    const float cs = fcos[s * 64 + p];
                    const float sn = fsin[s * 64 + p];
                    v = (n & 1) ? (part * sn + v * cs) : (v * cs - part * sn);
                }
                out[(size_t)m * E_DIM + n] = f2bf(v);
            }
        }
    }
}

// ---------------- output projection GEMM (fp32 out + bias) ----------------
__global__ __launch_bounds__(512, 2)
void out_gemm(const u16t* __restrict__ sh, const u16t* __restrict__ wob,
              const float* __restrict__ bo, float* __restrict__ out) {
    __shared__ u16t lds[65536];
    facc4 acc[8][4];
    int bm0, bn0; tile_swz(bm0, bn0);
    gemm256(sh, wob, bm0, bn0, lds, acc);

    const int t     = threadIdx.x;
    const int lane  = t & 63;
    const int m16   = lane & 15;
    const int quad  = lane >> 4;
    const int wid   = t >> 6;
    const int wid_m = wid >> 2;
    const int wid_n = wid & 3;

#pragma unroll
    for (int i = 0; i < 8; ++i) {
#pragma unroll
        for (int j = 0; j < 4; ++j) {
            const int n = bn0 + wid_n * 64 + j * 16 + m16;
            const float bn_ = bo[n];
#pragma unroll
            for (int r = 0; r < 4; ++r) {
                const int m = bm0 + wid_m * 128 + i * 16 + quad * 4 + r;
                out[(size_t)m * E_DIM + n] = acc[i][j][r] + bn_;
            }
        }
    }
}

// ---------------- per-token head attention, MFMA version ----------------
// (unchanged from verified baseline)
__global__ __launch_bounds__(256)
void attn_kernel(const u16t* __restrict__ qb, const u16t* __restrict__ kb,
                 const u16t* __restrict__ vb, u16t* __restrict__ sh) {
    __shared__ u16t Vs[4][16 * 136];   // pad 136: 4-way worst on frag reads
    __shared__ u16t Pt[4][16 * 32];    // P in A-frag layout, cols 16..31 = 0

    const int t    = threadIdx.x;
    const int wid  = t >> 6;
    const int lane = t & 63;
    const int m16  = lane & 15;
    const int quad = lane >> 4;
    const int tk   = blockIdx.x * 4 + wid;
    const int b    = tk >> 11;
    const int s    = tk & (S_LEN - 1);
    const size_t row = (size_t)tk * E_DIM;

    // Q,K fragments straight from global (16B per lane per k-step)
    frag8 aq[4], ak[4];
    const u16t* qrow = qb + row + m16 * 128 + quad * 8;
    const u16t* krow = kb + row + m16 * 128 + quad * 8;
#pragma unroll
    for (int ks = 0; ks < 4; ++ks) {
        aq[ks] = *(const frag8*)(qrow + ks * 32);
        ak[ks] = *(const frag8*)(krow + ks * 32);
    }

    // V row -> LDS [16][136]
    u16t* vs = Vs[wid];
#pragma unroll
    for (int c = 0; c < 4; ++c) {
        const int e  = c * 512 + lane * 8;
        const int vr = e >> 7, vc = e & 127;
        *(uint4*)(vs + vr * 136 + vc) = *(const uint4*)(vb + row + e);
    }

    // scores
    facc4 sacc = facc4{0.f, 0.f, 0.f, 0.f};
#pragma unroll
    for (int ks = 0; ks < 4; ++ks)
        sacc = __builtin_amdgcn_mfma_f32_16x16x32_bf16(aq[ks], ak[ks], sacc, 0, 0, 0);

    // softmax over g (16 lanes of the same quad); lane holds rows h=quad*4+r at col g=m16
    float p[4], mx[4], sm[4];
#pragma unroll
    for (int r = 0; r < 4; ++r) { p[r] = sacc[r] * 0.08838834764831845f; mx[r] = p[r]; }
#pragma unroll
    for (int msk = 1; msk < 16; msk <<= 1)
#pragma unroll
        for (int r = 0; r < 4; ++r) mx[r] = fmaxf(mx[r], __shfl_xor(mx[r], msk, 64));
#pragma unroll
    for (int r = 0; r < 4; ++r) { p[r] = __expf(p[r] - mx[r]); sm[r] = p[r]; }
#pragma unroll
    for (int msk = 1; msk < 16; msk <<= 1)
#pragma unroll
        for (int r = 0; r < 4; ++r) sm[r] += __shfl_xor(sm[r], msk, 64);

    // P -> LDS in A-frag layout: Pt[h][g], h rows of 32 (cols 16..31 zero)
    u16t* pt = Pt[wid];
#pragma unroll
    for (int r = 0; r < 4; ++r)
        pt[(quad * 4 + r) * 32 + m16] = f2bf(p[r] / sm[r]);
    *(uint2*)(pt + m16 * 32 + 16 + quad * 4) = uint2{0u, 0u};   // zero pad

    __syncthreads();

    // A-frag of P: lane holds P[m16][quad*8+j]
    const frag8 aP = *(const frag8*)(pt + m16 * 32 + quad * 8);

    // PV: 8 d-blocks of 16; B-frag j: V[(quad*8+j)&15][dblk*16+m16]
    facc4 oacc[8];
#pragma unroll
    for (int d = 0; d < 8; ++d) oacc[d] = facc4{0.f, 0.f, 0.f, 0.f};
#pragma unroll
    for (int dblk = 0; dblk < 8; ++dblk) {
        union { u16t u[8]; frag8 f; } bb;
#pragma unroll
        for (int j = 0; j < 8; ++j)
            bb.u[j] = vs[((quad * 8 + j) & 15) * 136 + dblk * 16 + m16];
        oacc[dblk] = __builtin_amdgcn_mfma_f32_16x16x32_bf16(aP, bb.f, oacc[dblk], 0, 0, 0);
    }

    // scatter to shuffled layout: lane holds out[h=quad*4+r][d=dblk*16+m16]
    const size_t base = ((size_t)b << 22) + (size_t)(s >> 4) * E_DIM
                      + (size_t)((s & 15) * 128);
#pragma unroll
    for (int dblk = 0; dblk < 8; ++dblk) {
        const int d = dblk * 16 + m16;
#pragma unroll
        for (int r = 0; r < 4; ++r) {
            const int h = quad * 4 + r;
            sh[base + ((size_t)h << 18) + d] = f2bf(oacc[dblk][r]);
        }
    }
}

// ---------------- launch ----------------
extern "C" void kernel_launch(void* const* d_in, const int* in_sizes, int n_in,
                              void* d_out, int out_size, void* d_ws, size_t ws_size,
                              hipStream_t stream) {
    const float* x    = (const float*)d_in[0];
    const float* fcos = (const float*)d_in[1];
    const float* fsin = (const float*)d_in[2];
    const float* wq   = (const float*)d_in[3];
    const float* bq   = (const float*)d_in[4];
    const float* wk   = (const float*)d_in[5];
    const float* bk   = (const float*)d_in[6];
    const float* wv   = (const float*)d_in[7];
    const float* bv   = (const float*)d_in[8];
    const float* wo   = (const float*)d_in[9];
    const float* bo   = (const float*)d_in[10];
    float* out = (float*)d_out;

    char* ws = (char*)d_ws;
    u16t* xb  = (u16t*)(ws);                      // 32 MB, reused as shuffled buf
    u16t* qb  = (u16t*)(ws + 33554432ull);
    u16t* kb  = (u16t*)(ws + 67108864ull);
    u16t* vb  = (u16t*)(ws + 100663296ull);
    u16t* wqb = (u16t*)(ws + 134217728ull);
    u16t* wkb = (u16t*)(ws + 142606336ull);
    u16t* wvb = (u16t*)(ws + 150994944ull);
    u16t* wob = (u16t*)(ws + 159383552ull);       // total 160 MB

    cvt_kernel<<<16384, 256, 0, stream>>>(x, xb, 4194304);
    cvt_kernel<<<4096, 256, 0, stream>>>(wq, wqb, 1048576);
    cvt_kernel<<<4096, 256, 0, stream>>>(wk, wkb, 1048576);
    cvt_kernel<<<4096, 256, 0, stream>>>(wv, wvb, 1048576);
    cvt_kernel<<<4096, 256, 0, stream>>>(wo, wob, 1048576);

    QkvArgs qa;
    qa.w[0] = wqb; qa.w[1] = wkb; qa.w[2] = wvb;
    qa.bias[0] = bq; qa.bias[1] = bk; qa.bias[2] = bv;
    qa.out[0] = qb; qa.out[1] = kb; qa.out[2] = vb;
    qkv_gemm<<<dim3(8, 32, 3), 512, 0, stream>>>(xb, qa, fcos, fsin);

    attn_kernel<<<2048, 256, 0, stream>>>(qb, kb, vb, xb);

    out_gemm<<<dim3(8, 32), 512, 0, stream>>>(xb, wob, bo, out);
}

// Round 2
// 492.578 us; speedup vs baseline: 1.0431x; 1.0131x over previous
//
#include <hip/hip_runtime.h>
#include <stdint.h>

typedef unsigned short u16t;
typedef __attribute__((ext_vector_type(8))) short frag8;   // 8 x bf16 (4 VGPRs)
typedef __attribute__((ext_vector_type(4))) float facc4;   // MFMA accumulator

#define S_LEN 2048
#define E_DIM 2048

__device__ __forceinline__ u16t f2bf(float f) {
    union { float f; uint32_t u; } c; c.f = f;
    return (u16t)((c.u + 0x7fffu + ((c.u >> 16) & 1u)) >> 16);  // RNE
}

// ---------------- fp32 -> bf16 conversion (vectorized) ----------------
__global__ __launch_bounds__(256) void cvt_kernel(const float* __restrict__ src,
                                                  u16t* __restrict__ dst, int n4) {
    int i = blockIdx.x * 256 + threadIdx.x;
    if (i >= n4) return;
    float4 v = ((const float4*)src)[i];
    ushort4 o;
    o.x = f2bf(v.x); o.y = f2bf(v.y); o.z = f2bf(v.z); o.w = f2bf(v.w);
    ((ushort4*)dst)[i] = o;
}

// ---------------- async global->LDS, 16B per lane ----------------
__device__ __forceinline__ void gldl16(const u16t* g, u16t* l) {
    __builtin_amdgcn_global_load_lds(
        (__attribute__((address_space(1))) void*)(g),
        (__attribute__((address_space(3))) void*)(l), 16, 0, 0);
}

// =====================================================================
// 256x256 8-phase GEMM core (faithful m201-template port):
//   C[256x256] = A[256xK] * B[256xK]^T, 8 waves (2M x 4N), per-wave 128x64.
// K-tiles processed in PAIRS: even tile lives in buf0 (L+0), odd in buf1
// (L+32768) -- fixed, no toggling. 8 phases per pair; phase p:
//   { ds_read frags ; stage half-tile freed at phase p-1 (2x gldl16) ;
//     [p==3,7: s_waitcnt vmcnt(6)] ; s_barrier ;
//     setprio(1) ; 16 MFMA ; setprio(0) ; s_barrier }
// Stage ledger (verified): steady state keeps exactly 3 half-tiles (6 loads)
// in flight across every barrier; vmcnt(6) at p3 forces completion of the
// odd tile's halves (staged p5,p6,p7 prev pair + p0 this pair), vmcnt(6) at
// p7 forces the next even tile's halves (staged p1..p4 this pair). Every
// stage-issue into region R is after the barrier-pair following R's last
// read. LDS layout per buf: Ak0 +0, Ak1 +8192, Bk0 +16384, Bk1 +24576 (u16).
// XOR-swizzle (T2) via pre-swizzled global source + swizzled ds_read, as
// before (bank conflicts measured 0).
// =====================================================================
__device__ __forceinline__ void gemm256(const u16t* __restrict__ A,
                                        const u16t* __restrict__ B,
                                        int bm0, int bn0,
                                        u16t* L, facc4 acc[8][4]) {
    const int t     = threadIdx.x;
    const int lane  = t & 63;
    const int wid   = t >> 6;
    const int m16   = lane & 15;
    const int quad  = lane >> 4;
    const int wid_m = wid >> 2;     // 0..1
    const int wid_n = wid & 3;      // 0..3

#pragma unroll
    for (int i = 0; i < 8; ++i)
#pragma unroll
        for (int j = 0; j < 4; ++j) acc[i][j] = facc4{0.f, 0.f, 0.f, 0.f};

    // ---- frag read offsets (u16 units), swizzled ----
    const int colA = (((wid_m << 2) + quad) ^ (m16 & 7)) << 3;
    const int colB = ((((wid_n >> 1) << 2) + quad) ^ (m16 & 7)) << 3;
    const int roA  = m16 * 64 + colA;                        // + i*1024
    const int roB  = ((wid_n & 1) * 64 + m16) * 64 + colB;   // + j*1024

    // ---- staging lane geometry (inverse swizzle on global source) ----
    const int cp    = (lane & 7) ^ (lane >> 3);
    const int rgrp  = cp >> 2;
    const int qq    = cp & 3;
    const int line0 = wid * 8 + (lane >> 3);
    const u16t* pA[2]; const u16t* pB[2];
    const int dOf0 = wid * 512;          // u16 offset within an 8192-u16 region
    const int dOf1 = 4096 + wid * 512;
#pragma unroll
    for (int ld = 0; ld < 2; ++ld) {
        const int grow = rgrp * 128 + ld * 64 + line0;   // row within 256-tile
        pA[ld] = A + (size_t)(bm0 + grow) * E_DIM + qq * 8;
        pB[ld] = B + (size_t)(bn0 + grow) * E_DIM + qq * 8;
    }

#define STG(P, K, DST) { gldl16(P[0] + (K), (DST) + dOf0); \
                         gldl16(P[1] + (K), (DST) + dOf1); }
#define CBAR { asm volatile("" ::: "memory"); \
               __builtin_amdgcn_s_barrier(); \
               asm volatile("" ::: "memory"); }
#define RDB(BASE) { _Pragma("unroll") \
    for (int j = 0; j < 4; ++j) bv[j] = *(const frag8*)((BASE) + roB + j * 1024); }
#define RDA0(BASE) { _Pragma("unroll") \
    for (int i = 0; i < 4; ++i) av[i] = *(const frag8*)((BASE) + roA + i * 1024); }
#define RDA4(BASE) { _Pragma("unroll") \
    for (int i = 0; i < 4; ++i) av[i] = *(const frag8*)((BASE) + roA + (i + 4) * 1024); }
#define MFMA16(IB) { __builtin_amdgcn_s_setprio(1); \
    _Pragma("unroll") for (int i = 0; i < 4; ++i) \
    _Pragma("unroll") for (int j = 0; j < 4; ++j) \
        acc[i + IB][j] = __builtin_amdgcn_mfma_f32_16x16x32_bf16( \
            av[i], bv[j], acc[i + IB][j], 0, 0, 0); \
    __builtin_amdgcn_s_setprio(0); }

    // ---- prologue: stage 7 half-tiles in steady-state order (p1..p7) ----
    STG(pB, 0,  L + 16384)            // buf0.Bk0  (tile 0)
    STG(pA, 0,  L + 0)                // buf0.Ak0
    STG(pB, 32, L + 24576)            // buf0.Bk1
    STG(pA, 32, L + 8192)             // buf0.Ak1
    STG(pB, 64, L + 32768 + 16384)    // buf1.Bk0  (tile 1)
    STG(pA, 64, L + 32768)            // buf1.Ak0
    STG(pB, 96, L + 32768 + 24576)    // buf1.Bk1
    asm volatile("s_waitcnt vmcnt(6)" ::: "memory");   // buf0 complete; 3 in flight
    CBAR

#pragma unroll 1
    for (int u = 0; u < 16; ++u) {
        const int kO1 = u * 128 + 96;                    // odd tile ksub1 (this pair)
        const int kE2 = (u < 15) ? u * 128 + 128 : 0;    // next even tile
        const int kO2 = (u < 15) ? u * 128 + 192 : 0;    // next odd tile
        frag8 av[4], bv[4];

        // ---- p0: even ksub0, rows 0-3 ----
        RDB(L + 16384) RDA0(L)
        STG(pA, kO1, L + 32768 + 8192)       // buf1.Ak1 (odd tile, read p6/p7)
        CBAR MFMA16(0) CBAR

        // ---- p1: even ksub0, rows 4-7 (bv reused) ----
        RDA4(L)
        STG(pB, kE2, L + 16384)              // buf0.Bk0 (next pair)
        CBAR MFMA16(4) CBAR

        // ---- p2: even ksub1, rows 0-3 ----
        RDB(L + 24576) RDA0(L + 8192)
        STG(pA, kE2, L)                      // buf0.Ak0
        CBAR MFMA16(0) CBAR

        // ---- p3: even ksub1, rows 4-7 ----
        RDA4(L + 8192)
        STG(pB, kE2 + 32, L + 24576)         // buf0.Bk1
        asm volatile("s_waitcnt vmcnt(6)" ::: "memory");
        CBAR MFMA16(4) CBAR

        // ---- p4: odd ksub0, rows 0-3 ----
        RDB(L + 32768 + 16384) RDA0(L + 32768)
        STG(pA, kE2 + 32, L + 8192)          // buf0.Ak1
        CBAR MFMA16(0) CBAR

        // ---- p5: odd ksub0, rows 4-7 ----
        RDA4(L + 32768)
        STG(pB, kO2, L + 32768 + 16384)      // buf1.Bk0 (next pair)
        CBAR MFMA16(4) CBAR

        // ---- p6: odd ksub1, rows 0-3 ----
        RDB(L + 32768 + 24576) RDA0(L + 32768 + 8192)
        STG(pA, kO2, L + 32768)              // buf1.Ak0
        CBAR MFMA16(0) CBAR

        // ---- p7: odd ksub1, rows 4-7 ----
        RDA4(L + 32768 + 8192)
        STG(pB, kO2 + 32, L + 32768 + 24576) // buf1.Bk1
        asm volatile("s_waitcnt vmcnt(6)" ::: "memory");
        CBAR MFMA16(4) CBAR
    }

    // drain tail prefetch before epilogue
    asm volatile("s_waitcnt vmcnt(0)" ::: "memory");

#undef STG
#undef CBAR
#undef RDB
#undef RDA0
#undef RDA4
#undef MFMA16
}

// bijective XCD-aware tile swizzle: 256 wgs per plane, 256 % 8 == 0.
__device__ __forceinline__ void tile_swz(int& bm0, int& bn0) {
    const int orig = blockIdx.y * 8 + blockIdx.x;
    const int swz  = (orig & 7) * 32 + (orig >> 3);
    bm0 = (swz >> 3) * 256;
    bn0 = (swz & 7) * 256;
}

// ---------------- fused QKV projection (+bias, +RoPE for q,k) ----------------
struct QkvArgs {
    const u16t* w[3];
    const float* bias[3];
    u16t* out[3];
};

__global__ __launch_bounds__(512, 2)
void qkv_gemm(const u16t* __restrict__ xb, QkvArgs args,
              const float* __restrict__ fcos, const float* __restrict__ fsin) {
    __shared__ u16t lds[65536];     // 128 KiB: 2 bufs x (A k0,k1 + B k0,k1)
    facc4 acc[8][4];
    int bm0, bn0; tile_swz(bm0, bn0);
    const int z = blockIdx.z;
    gemm256(xb, args.w[z], bm0, bn0, lds, acc);

    const int t     = threadIdx.x;
    const int lane  = t & 63;
    const int m16   = lane & 15;
    const int quad  = lane >> 4;
    const int wid   = t >> 6;
    const int wid_m = wid >> 2;
    const int wid_n = wid & 3;
    const bool rope = (z < 2);
    u16t* out = args.out[z];
    const float* bias = args.bias[z];

#pragma unroll
    for (int i = 0; i < 8; ++i) {
#pragma unroll
        for (int j = 0; j < 4; ++j) {
            const int n = bn0 + wid_n * 64 + j * 16 + m16;
            const float bn_ = bias[n];
#pragma unroll
            for (int r = 0; r < 4; ++r) {
                const int m = bm0 + wid_m * 128 + i * 16 + quad * 4 + r;
                float v = acc[i][j][r] + bn_;
                // RoPE: pair partner (n^1) lives in lane^1 (same quad, same reg)
                const float part = __shfl_xor(v, 1, 64);
                if (rope) {
                    const int s = m & (S_LEN - 1);
                    const int p = (n & 127) >> 1;
                    const float cs = fcos[s * 64 + p];
                    const float sn = fsin[s * 64 + p];
                    v = (n & 1) ? (part * sn + v * cs) : (v * cs - part * sn);
                }
                out[(size_t)m * E_DIM + n] = f2bf(v);
            }
        }
    }
}

// ---------------- output projection GEMM (fp32 out + bias) ----------------
__global__ __launch_bounds__(512, 2)
void out_gemm(const u16t* __restrict__ sh, const u16t* __restrict__ wob,
              const float* __restrict__ bo, float* __restrict__ out) {
    __shared__ u16t lds[65536];
    facc4 acc[8][4];
    int bm0, bn0; tile_swz(bm0, bn0);
    gemm256(sh, wob, bm0, bn0, lds, acc);

    const int t     = threadIdx.x;
    const int lane  = t & 63;
    const int m16   = lane & 15;
    const int quad  = lane >> 4;
    const int wid   = t >> 6;
    const int wid_m = wid >> 2;
    const int wid_n = wid & 3;

#pragma unroll
    for (int i = 0; i < 8; ++i) {
#pragma unroll
        for (int j = 0; j < 4; ++j) {
            const int n = bn0 + wid_n * 64 + j * 16 + m16;
            const float bn_ = bo[n];
#pragma unroll
            for (int r = 0; r < 4; ++r) {
                const int m = bm0 + wid_m * 128 + i * 16 + quad * 4 + r;
                out[(size_t)m * E_DIM + n] = acc[i][j][r] + bn_;
            }
        }
    }
}

// ---------------- per-token head attention, MFMA version ----------------
// (unchanged from verified baseline)
__global__ __launch_bounds__(256)
void attn_kernel(const u16t* __restrict__ qb, const u16t* __restrict__ kb,
                 const u16t* __restrict__ vb, u16t* __restrict__ sh) {
    __shared__ u16t Vs[4][16 * 136];   // pad 136: 4-way worst on frag reads
    __shared__ u16t Pt[4][16 * 32];    // P in A-frag layout, cols 16..31 = 0

    const int t    = threadIdx.x;
    const int wid  = t >> 6;
    const int lane = t & 63;
    const int m16  = lane & 15;
    const int quad = lane >> 4;
    const int tk   = blockIdx.x * 4 + wid;
    const int b    = tk >> 11;
    const int s    = tk & (S_LEN - 1);
    const size_t row = (size_t)tk * E_DIM;

    // Q,K fragments straight from global (16B per lane per k-step)
    frag8 aq[4], ak[4];
    const u16t* qrow = qb + row + m16 * 128 + quad * 8;
    const u16t* krow = kb + row + m16 * 128 + quad * 8;
#pragma unroll
    for (int ks = 0; ks < 4; ++ks) {
        aq[ks] = *(const frag8*)(qrow + ks * 32);
        ak[ks] = *(const frag8*)(krow + ks * 32);
    }

    // V row -> LDS [16][136]
    u16t* vs = Vs[wid];
#pragma unroll
    for (int c = 0; c < 4; ++c) {
        const int e  = c * 512 + lane * 8;
        const int vr = e >> 7, vc = e & 127;
        *(uint4*)(vs + vr * 136 + vc) = *(const uint4*)(vb + row + e);
    }

    // scores
    facc4 sacc = facc4{0.f, 0.f, 0.f, 0.f};
#pragma unroll
    for (int ks = 0; ks < 4; ++ks)
        sacc = __builtin_amdgcn_mfma_f32_16x16x32_bf16(aq[ks], ak[ks], sacc, 0, 0, 0);

    // softmax over g (16 lanes of the same quad); lane holds rows h=quad*4+r at col g=m16
    float p[4], mx[4], sm[4];
#pragma unroll
    for (int r = 0; r < 4; ++r) { p[r] = sacc[r] * 0.08838834764831845f; mx[r] = p[r]; }
#pragma unroll
    for (int msk = 1; msk < 16; msk <<= 1)
#pragma unroll
        for (int r = 0; r < 4; ++r) mx[r] = fmaxf(mx[r], __shfl_xor(mx[r], msk, 64));
#pragma unroll
    for (int r = 0; r < 4; ++r) { p[r] = __expf(p[r] - mx[r]); sm[r] = p[r]; }
#pragma unroll
    for (int msk = 1; msk < 16; msk <<= 1)
#pragma unroll
        for (int r = 0; r < 4; ++r) sm[r] += __shfl_xor(sm[r], msk, 64);

    // P -> LDS in A-frag layout: Pt[h][g], h rows of 32 (cols 16..31 zero)
    u16t* pt = Pt[wid];
#pragma unroll
    for (int r = 0; r < 4; ++r)
        pt[(quad * 4 + r) * 32 + m16] = f2bf(p[r] / sm[r]);
    *(uint2*)(pt + m16 * 32 + 16 + quad * 4) = uint2{0u, 0u};   // zero pad

    __syncthreads();

    // A-frag of P: lane holds P[m16][quad*8+j]
    const frag8 aP = *(const frag8*)(pt + m16 * 32 + quad * 8);

    // PV: 8 d-blocks of 16; B-frag j: V[(quad*8+j)&15][dblk*16+m16]
    facc4 oacc[8];
#pragma unroll
    for (int d = 0; d < 8; ++d) oacc[d] = facc4{0.f, 0.f, 0.f, 0.f};
#pragma unroll
    for (int dblk = 0; dblk < 8; ++dblk) {
        union { u16t u[8]; frag8 f; } bb;
#pragma unroll
        for (int j = 0; j < 8; ++j)
            bb.u[j] = vs[((quad * 8 + j) & 15) * 136 + dblk * 16 + m16];
        oacc[dblk] = __builtin_amdgcn_mfma_f32_16x16x32_bf16(aP, bb.f, oacc[dblk], 0, 0, 0);
    }

    // scatter to shuffled layout: lane holds out[h=quad*4+r][d=dblk*16+m16]
    const size_t base = ((size_t)b << 22) + (size_t)(s >> 4) * E_DIM
                      + (size_t)((s & 15) * 128);
#pragma unroll
    for (int dblk = 0; dblk < 8; ++dblk) {
        const int d = dblk * 16 + m16;
#pragma unroll
        for (int r = 0; r < 4; ++r) {
            const int h = quad * 4 + r;
            sh[base + ((size_t)h << 18) + d] = f2bf(oacc[dblk][r]);
        }
    }
}

// ---------------- launch ----------------
extern "C" void kernel_launch(void* const* d_in, const int* in_sizes, int n_in,
                              void* d_out, int out_size, void* d_ws, size_t ws_size,
                              hipStream_t stream) {
    const float* x    = (const float*)d_in[0];
    const float* fcos = (const float*)d_in[1];
    const float* fsin = (const float*)d_in[2];
    const float* wq   = (const float*)d_in[3];
    const float* bq   = (const float*)d_in[4];
    const float* wk   = (const float*)d_in[5];
    const float* bk   = (const float*)d_in[6];
    const float* wv   = (const float*)d_in[7];
    const float* bv   = (const float*)d_in[8];
    const float* wo   = (const float*)d_in[9];
    const float* bo   = (const float*)d_in[10];
    float* out = (float*)d_out;

    char* ws = (char*)d_ws;
    u16t* xb  = (u16t*)(ws);                      // 32 MB, reused as shuffled buf
    u16t* qb  = (u16t*)(ws + 33554432ull);
    u16t* kb  = (u16t*)(ws + 67108864ull);
    u16t* vb  = (u16t*)(ws + 100663296ull);
    u16t* wqb = (u16t*)(ws + 134217728ull);
    u16t* wkb = (u16t*)(ws + 142606336ull);
    u16t* wvb = (u16t*)(ws + 150994944ull);
    u16t* wob = (u16t*)(ws + 159383552ull);       // total 160 MB

    cvt_kernel<<<16384, 256, 0, stream>>>(x, xb, 4194304);
    cvt_kernel<<<4096, 256, 0, stream>>>(wq, wqb, 1048576);
    cvt_kernel<<<4096, 256, 0, stream>>>(wk, wkb, 1048576);
    cvt_kernel<<<4096, 256, 0, stream>>>(wv, wvb, 1048576);
    cvt_kernel<<<4096, 256, 0, stream>>>(wo, wob, 1048576);

    QkvArgs qa;
    qa.w[0] = wqb; qa.w[1] = wkb; qa.w[2] = wvb;
    qa.bias[0] = bq; qa.bias[1] = bk; qa.bias[2] = bv;
    qa.out[0] = qb; qa.out[1] = kb; qa.out[2] = vb;
    qkv_gemm<<<dim3(8, 32, 3), 512, 0, stream>>>(xb, qa, fcos, fsin);

    attn_kernel<<<2048, 256, 0, stream>>>(qb, kb, vb, xb);

    out_gemm<<<dim3(8, 32), 512, 0, stream>>>(xb, wob, bo, out);
}

// Round 3
// 491.478 us; speedup vs baseline: 1.0454x; 1.0022x over previous
//
#include <hip/hip_runtime.h>
#include <stdint.h>

typedef unsigned short u16t;
typedef __attribute__((ext_vector_type(8))) short frag8;   // 8 x bf16 (4 VGPRs)
typedef __attribute__((ext_vector_type(4))) float facc4;   // MFMA accumulator

#define S_LEN 2048
#define E_DIM 2048

__device__ __forceinline__ u16t f2bf(float f) {
    union { float f; uint32_t u; } c; c.f = f;
    return (u16t)((c.u + 0x7fffu + ((c.u >> 16) & 1u)) >> 16);  // RNE
}

// ---------------- fp32 -> bf16 conversion (vectorized) ----------------
__global__ __launch_bounds__(256) void cvt_kernel(const float* __restrict__ src,
                                                  u16t* __restrict__ dst, int n4) {
    int i = blockIdx.x * 256 + threadIdx.x;
    if (i >= n4) return;
    float4 v = ((const float4*)src)[i];
    ushort4 o;
    o.x = f2bf(v.x); o.y = f2bf(v.y); o.z = f2bf(v.z); o.w = f2bf(v.w);
    ((ushort4*)dst)[i] = o;
}

// ---------------- async global->LDS, 16B per lane ----------------
__device__ __forceinline__ void gldl16(const u16t* g, u16t* l) {
    __builtin_amdgcn_global_load_lds(
        (__attribute__((address_space(1))) void*)(g),
        (__attribute__((address_space(3))) void*)(l), 16, 0, 0);
}

// =====================================================================
// 256x256 8-phase GEMM core with REGISTER READ-AHEAD:
//   C[256x256] = A[256xK] * B[256xK]^T, 8 waves (2M x 4N), per-wave 128x64.
// Phase p issues the ds_reads for phase p+1's fragments (double-buffered
// regs avA/avB, bv0/bv1) and then runs phase p's 16 MFMA -> the LDS read
// batch overlaps the 620-cyc MFMA block instead of serializing with it.
// One s_barrier per phase. vmcnt(6) at start of p1,p3,p5,p7 (wait at
// start-q forces completion through stage(q-4); covers every read's
// newest required stage: p1<-p4', p3<-p6', p5<-p0, p7<-p2; always keeps
// 3 half-tiles / 6 loads in flight -- never drains).
// Stage issue points (unchanged ledger from the passing R2 kernel):
//   p0: buf1.Ak1  p1: buf0.Bk0(next)  p2: buf0.Ak0  p3: buf0.Bk1
//   p4: buf0.Ak1  p5: buf1.Bk0(next)  p6: buf1.Ak0  p7: buf1.Bk1
// LDS per buf: Ak0 +0, Ak1 +8192, Bk0 +16384, Bk1 +24576 (u16); buf1 at
// +32768. XOR-swizzle (T2) via pre-swizzled global source + swizzled
// ds_read (bank conflicts measured 0). Accumulation order per acc element
// identical to R2 (even-k0, even-k1, odd-k0, odd-k1) -> same numerics.
// =====================================================================
__device__ __forceinline__ void gemm256(const u16t* __restrict__ A,
                                        const u16t* __restrict__ B,
                                        int bm0, int bn0,
                                        u16t* L, facc4 acc[8][4]) {
    const int t     = threadIdx.x;
    const int lane  = t & 63;
    const int wid   = t >> 6;
    const int m16   = lane & 15;
    const int quad  = lane >> 4;
    const int wid_m = wid >> 2;     // 0..1
    const int wid_n = wid & 3;      // 0..3

#pragma unroll
    for (int i = 0; i < 8; ++i)
#pragma unroll
        for (int j = 0; j < 4; ++j) acc[i][j] = facc4{0.f, 0.f, 0.f, 0.f};

    // ---- frag read offsets (u16 units), swizzled ----
    const int colA = (((wid_m << 2) + quad) ^ (m16 & 7)) << 3;
    const int colB = ((((wid_n >> 1) << 2) + quad) ^ (m16 & 7)) << 3;
    const int roA  = m16 * 64 + colA;                        // + i*1024
    const int roB  = ((wid_n & 1) * 64 + m16) * 64 + colB;   // + j*1024

    // ---- staging lane geometry (inverse swizzle on global source) ----
    const int cp    = (lane & 7) ^ (lane >> 3);
    const int rgrp  = cp >> 2;
    const int qq    = cp & 3;
    const int line0 = wid * 8 + (lane >> 3);
    const u16t* pA[2]; const u16t* pB[2];
    const int dOf0 = wid * 512;          // u16 offset within an 8192-u16 region
    const int dOf1 = 4096 + wid * 512;
#pragma unroll
    for (int ld = 0; ld < 2; ++ld) {
        const int grow = rgrp * 128 + ld * 64 + line0;   // row within 256-tile
        pA[ld] = A + (size_t)(bm0 + grow) * E_DIM + qq * 8;
        pB[ld] = B + (size_t)(bn0 + grow) * E_DIM + qq * 8;
    }

    frag8 avA[4], avB[4], bv0[4], bv1[4];

#define STG(P, K, DST) { gldl16(P[0] + (K), (DST) + dOf0); \
                         gldl16(P[1] + (K), (DST) + dOf1); }
#define BARR { asm volatile("" ::: "memory"); \
               __builtin_amdgcn_s_barrier(); \
               asm volatile("" ::: "memory"); }
#define VM6 asm volatile("s_waitcnt vmcnt(6)" ::: "memory");
#define RDB(DST, BASE) { _Pragma("unroll") \
    for (int j = 0; j < 4; ++j) DST[j] = *(const frag8*)((BASE) + roB + j * 1024); }
#define RDA(DST, BASE, IO) { _Pragma("unroll") \
    for (int i = 0; i < 4; ++i) DST[i] = *(const frag8*)((BASE) + roA + ((IO) + i) * 1024); }
#define MFMA16(IB, AV, BV) { __builtin_amdgcn_s_setprio(1); \
    _Pragma("unroll") for (int i = 0; i < 4; ++i) \
    _Pragma("unroll") for (int j = 0; j < 4; ++j) \
        acc[i + IB][j] = __builtin_amdgcn_mfma_f32_16x16x32_bf16( \
            AV[i], BV[j], acc[i + IB][j], 0, 0, 0); \
    __builtin_amdgcn_s_setprio(0); }

    // ---- prologue: stage 7 half-tiles (buf0 full + buf1 Bk0,Ak0,Bk1) ----
    STG(pB, 0,  L + 16384)            // buf0.Bk0  (tile 0)
    STG(pA, 0,  L + 0)                // buf0.Ak0
    STG(pB, 32, L + 24576)            // buf0.Bk1
    STG(pA, 32, L + 8192)             // buf0.Ak1
    STG(pB, 64, L + 32768 + 16384)    // buf1.Bk0  (tile 1)
    STG(pA, 64, L + 32768)            // buf1.Ak0
    STG(pB, 96, L + 32768 + 24576)    // buf1.Bk1
    VM6                               // forces all of buf0; 3 halves in flight
    BARR
    // pre-read p0 fragments: Bk0(buf0) + Ak0(buf0) rows 0-3
    RDB(bv0, L + 16384)
    RDA(avA, L + 0, 0)

#pragma unroll 1
    for (int u = 0; u < 16; ++u) {
        const int kO1 = u * 128 + 96;                    // odd tile ksub1 (this pair)
        const int kE2 = (u < 15) ? u * 128 + 128 : 0;    // next even tile
        const int kO2 = (u < 15) ? u * 128 + 192 : 0;    // next odd tile

        // ---- p0: MFMA even-k0 rows0-3 ; read Ak0 r4-7 ; stage buf1.Ak1 ----
        BARR
        RDA(avB, L + 0, 4)
        STG(pA, kO1, L + 32768 + 8192)
        MFMA16(0, avA, bv0)

        // ---- p1: MFMA even-k0 rows4-7 ; read Bk1+Ak1 r0-3 ; stage buf0.Bk0 ----
        VM6
        BARR
        RDB(bv1, L + 24576)
        RDA(avA, L + 8192, 0)
        STG(pB, kE2, L + 16384)
        MFMA16(4, avB, bv0)

        // ---- p2: MFMA even-k1 rows0-3 ; read Ak1 r4-7 ; stage buf0.Ak0 ----
        BARR
        RDA(avB, L + 8192, 4)
        STG(pA, kE2, L + 0)
        MFMA16(0, avA, bv1)

        // ---- p3: MFMA even-k1 rows4-7 ; read buf1 Bk0+Ak0 r0-3 ; stage buf0.Bk1 ----
        VM6
        BARR
        RDB(bv0, L + 32768 + 16384)
        RDA(avA, L + 32768, 0)
        STG(pB, kE2 + 32, L + 24576)
        MFMA16(4, avB, bv1)

        // ---- p4: MFMA odd-k0 rows0-3 ; read buf1 Ak0 r4-7 ; stage buf0.Ak1 ----
        BARR
        RDA(avB, L + 32768, 4)
        STG(pA, kE2 + 32, L + 8192)
        MFMA16(0, avA, bv0)

        // ---- p5: MFMA odd-k0 rows4-7 ; read buf1 Bk1+Ak1 r0-3 ; stage buf1.Bk0 ----
        VM6
        BARR
        RDB(bv1, L + 32768 + 24576)
        RDA(avA, L + 32768 + 8192, 0)
        STG(pB, kO2, L + 32768 + 16384)
        MFMA16(4, avB, bv0)

        // ---- p6: MFMA odd-k1 rows0-3 ; read buf1 Ak1 r4-7 ; stage buf1.Ak0 ----
        BARR
        RDA(avB, L + 32768 + 8192, 4)
        STG(pA, kO2, L + 32768)
        MFMA16(0, avA, bv1)

        // ---- p7: MFMA odd-k1 rows4-7 ; read next buf0 Bk0+Ak0 r0-3 ; stage buf1.Bk1 ----
        VM6
        BARR
        RDB(bv0, L + 16384)
        RDA(avA, L + 0, 0)
        STG(pB, kO2 + 32, L + 32768 + 24576)
        MFMA16(4, avB, bv1)
    }

    // drain tail prefetch before epilogue
    asm volatile("s_waitcnt vmcnt(0)" ::: "memory");

#undef STG
#undef BARR
#undef VM6
#undef RDB
#undef RDA
#undef MFMA16
}

// bijective XCD-aware tile swizzle: 256 wgs per plane, 256 % 8 == 0.
__device__ __forceinline__ void tile_swz(int& bm0, int& bn0) {
    const int orig = blockIdx.y * 8 + blockIdx.x;
    const int swz  = (orig & 7) * 32 + (orig >> 3);
    bm0 = (swz >> 3) * 256;
    bn0 = (swz & 7) * 256;
}

// ---------------- fused QKV projection (+bias, +RoPE for q,k) ----------------
struct QkvArgs {
    const u16t* w[3];
    const float* bias[3];
    u16t* out[3];
};

__global__ __launch_bounds__(512, 2)
void qkv_gemm(const u16t* __restrict__ xb, QkvArgs args,
              const float* __restrict__ fcos, const float* __restrict__ fsin) {
    __shared__ u16t lds[65536];     // 128 KiB: 2 bufs x (A k0,k1 + B k0,k1)
    facc4 acc[8][4];
    int bm0, bn0; tile_swz(bm0, bn0);
    const int z = blockIdx.z;
    gemm256(xb, args.w[z], bm0, bn0, lds, acc);

    const int t     = threadIdx.x;
    const int lane  = t & 63;
    const int m16   = lane & 15;
    const int quad  = lane >> 4;
    const int wid   = t >> 6;
    const int wid_m = wid >> 2;
    const int wid_n = wid & 3;
    const bool rope = (z < 2);
    u16t* out = args.out[z];
    const float* bias = args.bias[z];

#pragma unroll
    for (int i = 0; i < 8; ++i) {
#pragma unroll
        for (int j = 0; j < 4; ++j) {
            const int n = bn0 + wid_n * 64 + j * 16 + m16;
            const float bn_ = bias[n];
#pragma unroll
            for (int r = 0; r < 4; ++r) {
                const int m = bm0 + wid_m * 128 + i * 16 + quad * 4 + r;
                float v = acc[i][j][r] + bn_;
                // RoPE: pair partner (n^1) lives in lane^1 (same quad, same reg)
                const float part = __shfl_xor(v, 1, 64);
                if (rope) {
                    const int s = m & (S_LEN - 1);
                    const int p = (n & 127) >> 1;
                    const float cs = fcos[s * 64 + p];
                    const float sn = fsin[s * 64 + p];
                    v = (n & 1) ? (part * sn + v * cs) : (v * cs - part * sn);
                }
                out[(size_t)m * E_DIM + n] = f2bf(v);
            }
        }
    }
}

// ---------------- output projection GEMM (fp32 out + bias) ----------------
__global__ __launch_bounds__(512, 2)
void out_gemm(const u16t* __restrict__ sh, const u16t* __restrict__ wob,
              const float* __restrict__ bo, float* __restrict__ out) {
    __shared__ u16t lds[65536];
    facc4 acc[8][4];
    int bm0, bn0; tile_swz(bm0, bn0);
    gemm256(sh, wob, bm0, bn0, lds, acc);

    const int t     = threadIdx.x;
    const int lane  = t & 63;
    const int m16   = lane & 15;
    const int quad  = lane >> 4;
    const int wid   = t >> 6;
    const int wid_m = wid >> 2;
    const int wid_n = wid & 3;

#pragma unroll
    for (int i = 0; i < 8; ++i) {
#pragma unroll
        for (int j = 0; j < 4; ++j) {
            const int n = bn0 + wid_n * 64 + j * 16 + m16;
            const float bn_ = bo[n];
#pragma unroll
            for (int r = 0; r < 4; ++r) {
                const int m = bm0 + wid_m * 128 + i * 16 + quad * 4 + r;
                out[(size_t)m * E_DIM + n] = acc[i][j][r] + bn_;
            }
        }
    }
}

// ---------------- per-token head attention, MFMA version ----------------
// (unchanged from verified baseline)
__global__ __launch_bounds__(256)
void attn_kernel(const u16t* __restrict__ qb, const u16t* __restrict__ kb,
                 const u16t* __restrict__ vb, u16t* __restrict__ sh) {
    __shared__ u16t Vs[4][16 * 136];   // pad 136: 4-way worst on frag reads
    __shared__ u16t Pt[4][16 * 32];    // P in A-frag layout, cols 16..31 = 0

    const int t    = threadIdx.x;
    const int wid  = t >> 6;
    const int lane = t & 63;
    const int m16  = lane & 15;
    const int quad = lane >> 4;
    const int tk   = blockIdx.x * 4 + wid;
    const int b    = tk >> 11;
    const int s    = tk & (S_LEN - 1);
    const size_t row = (size_t)tk * E_DIM;

    // Q,K fragments straight from global (16B per lane per k-step)
    frag8 aq[4], ak[4];
    const u16t* qrow = qb + row + m16 * 128 + quad * 8;
    const u16t* krow = kb + row + m16 * 128 + quad * 8;
#pragma unroll
    for (int ks = 0; ks < 4; ++ks) {
        aq[ks] = *(const frag8*)(qrow + ks * 32);
        ak[ks] = *(const frag8*)(krow + ks * 32);
    }

    // V row -> LDS [16][136]
    u16t* vs = Vs[wid];
#pragma unroll
    for (int c = 0; c < 4; ++c) {
        const int e  = c * 512 + lane * 8;
        const int vr = e >> 7, vc = e & 127;
        *(uint4*)(vs + vr * 136 + vc) = *(const uint4*)(vb + row + e);
    }

    // scores
    facc4 sacc = facc4{0.f, 0.f, 0.f, 0.f};
#pragma unroll
    for (int ks = 0; ks < 4; ++ks)
        sacc = __builtin_amdgcn_mfma_f32_16x16x32_bf16(aq[ks], ak[ks], sacc, 0, 0, 0);

    // softmax over g (16 lanes of the same quad); lane holds rows h=quad*4+r at col g=m16
    float p[4], mx[4], sm[4];
#pragma unroll
    for (int r = 0; r < 4; ++r) { p[r] = sacc[r] * 0.08838834764831845f; mx[r] = p[r]; }
#pragma unroll
    for (int msk = 1; msk < 16; msk <<= 1)
#pragma unroll
        for (int r = 0; r < 4; ++r) mx[r] = fmaxf(mx[r], __shfl_xor(mx[r], msk, 64));
#pragma unroll
    for (int r = 0; r < 4; ++r) { p[r] = __expf(p[r] - mx[r]); sm[r] = p[r]; }
#pragma unroll
    for (int msk = 1; msk < 16; msk <<= 1)
#pragma unroll
        for (int r = 0; r < 4; ++r) sm[r] += __shfl_xor(sm[r], msk, 64);

    // P -> LDS in A-frag layout: Pt[h][g], h rows of 32 (cols 16..31 zero)
    u16t* pt = Pt[wid];
#pragma unroll
    for (int r = 0; r < 4; ++r)
        pt[(quad * 4 + r) * 32 + m16] = f2bf(p[r] / sm[r]);
    *(uint2*)(pt + m16 * 32 + 16 + quad * 4) = uint2{0u, 0u};   // zero pad

    __syncthreads();

    // A-frag of P: lane holds P[m16][quad*8+j]
    const frag8 aP = *(const frag8*)(pt + m16 * 32 + quad * 8);

    // PV: 8 d-blocks of 16; B-frag j: V[(quad*8+j)&15][dblk*16+m16]
    facc4 oacc[8];
#pragma unroll
    for (int d = 0; d < 8; ++d) oacc[d] = facc4{0.f, 0.f, 0.f, 0.f};
#pragma unroll
    for (int dblk = 0; dblk < 8; ++dblk) {
        union { u16t u[8]; frag8 f; } bb;
#pragma unroll
        for (int j = 0; j < 8; ++j)
            bb.u[j] = vs[((quad * 8 + j) & 15) * 136 + dblk * 16 + m16];
        oacc[dblk] = __builtin_amdgcn_mfma_f32_16x16x32_bf16(aP, bb.f, oacc[dblk], 0, 0, 0);
    }

    // scatter to shuffled layout: lane holds out[h=quad*4+r][d=dblk*16+m16]
    const size_t base = ((size_t)b << 22) + (size_t)(s >> 4) * E_DIM
                      + (size_t)((s & 15) * 128);
#pragma unroll
    for (int dblk = 0; dblk < 8; ++dblk) {
        const int d = dblk * 16 + m16;
#pragma unroll
        for (int r = 0; r < 4; ++r) {
            const int h = quad * 4 + r;
            sh[base + ((size_t)h << 18) + d] = f2bf(oacc[dblk][r]);
        }
    }
}

// ---------------- launch ----------------
extern "C" void kernel_launch(void* const* d_in, const int* in_sizes, int n_in,
                              void* d_out, int out_size, void* d_ws, size_t ws_size,
                              hipStream_t stream) {
    const float* x    = (const float*)d_in[0];
    const float* fcos = (const float*)d_in[1];
    const float* fsin = (const float*)d_in[2];
    const float* wq   = (const float*)d_in[3];
    const float* bq   = (const float*)d_in[4];
    const float* wk   = (const float*)d_in[5];
    const float* bk   = (const float*)d_in[6];
    const float* wv   = (const float*)d_in[7];
    const float* bv   = (const float*)d_in[8];
    const float* wo   = (const float*)d_in[9];
    const float* bo   = (const float*)d_in[10];
    float* out = (float*)d_out;

    char* ws = (char*)d_ws;
    u16t* xb  = (u16t*)(ws);                      // 32 MB, reused as shuffled buf
    u16t* qb  = (u16t*)(ws + 33554432ull);
    u16t* kb  = (u16t*)(ws + 67108864ull);
    u16t* vb  = (u16t*)(ws + 100663296ull);
    u16t* wqb = (u16t*)(ws + 134217728ull);
    u16t* wkb = (u16t*)(ws + 142606336ull);
    u16t* wvb = (u16t*)(ws + 150994944ull);
    u16t* wob = (u16t*)(ws + 159383552ull);       // total 160 MB

    cvt_kernel<<<16384, 256, 0, stream>>>(x, xb, 4194304);
    cvt_kernel<<<4096, 256, 0, stream>>>(wq, wqb, 1048576);
    cvt_kernel<<<4096, 256, 0, stream>>>(wk, wkb, 1048576);
    cvt_kernel<<<4096, 256, 0, stream>>>(wv, wvb, 1048576);
    cvt_kernel<<<4096, 256, 0, stream>>>(wo, wob, 1048576);

    QkvArgs qa;
    qa.w[0] = wqb; qa.w[1] = wkb; qa.w[2] = wvb;
    qa.bias[0] = bq; qa.bias[1] = bk; qa.bias[2] = bv;
    qa.out[0] = qb; qa.out[1] = kb; qa.out[2] = vb;
    qkv_gemm<<<dim3(8, 32, 3), 512, 0, stream>>>(xb, qa, fcos, fsin);

    attn_kernel<<<2048, 256, 0, stream>>>(qb, kb, vb, xb);

    out_gemm<<<dim3(8, 32), 512, 0, stream>>>(xb, wob, bo, out);
}